// Round 3
// baseline (86.155 us; speedup 1.0000x reference)
//
#include <hip/hip_runtime.h>

#define B 32
#define N 1024
#define D 256
#define H 8
#define E 256
#define HE 2048

// d_ws float offsets
#define OFF_XPART 0        // [B][8][D]        65536
#define OFF_KBAR  65536    // [B][HE]          65536
#define OFF_U     131072   // [B][H][D]        65536 (scale folded in)
#define OFF_VPART 196608   // [B][8c][H][D]    524288
#define OFF_VBAR  720896   // [B][H][D]        65536
#define OFF_ZPART 786432   // [B][8c][H]       2048
#define OFF_RES   788480   // [B][HE]          65536

#define DOT4(a, v) ((a).x * (v).x + (a).y * (v).y + (a).z * (v).z + (a).w * (v).w)

// ---- Xpart[b,p,d] = sum_{n in chunk p} wsum[n] * x[b,n,d]   (no atomics)
__global__ __launch_bounds__(256) void k_xbar(const float4* __restrict__ x4,
                                              const float* __restrict__ wsum,
                                              float* __restrict__ Xpart) {
    __shared__ float4 ps[4][64];
    int t = threadIdx.x, b = blockIdx.x, p = blockIdx.y;
    int dq = t & 63, rep = t >> 6;
    float4 acc = make_float4(0.f, 0.f, 0.f, 0.f);
    int nbase = p * 128 + rep * 32;
#pragma unroll 4
    for (int i = 0; i < 32; ++i) {
        int n = nbase + i;
        float w = wsum[n];
        float4 xv = x4[(size_t)(b * N + n) * 64 + dq];
        acc.x += w * xv.x; acc.y += w * xv.y; acc.z += w * xv.z; acc.w += w * xv.w;
    }
    ps[rep][dq] = acc;
    __syncthreads();
    if (t < 64) {
        float4 s = ps[0][t], s1 = ps[1][t], s2 = ps[2][t], s3 = ps[3][t];
        s.x += s1.x + s2.x + s3.x; s.y += s1.y + s2.y + s3.y;
        s.z += s1.z + s2.z + s3.z; s.w += s1.w + s2.w + s3.w;
        *(float4*)&Xpart[(size_t)(b * 8 + p) * D + t * 4] = s;
    }
}

// ---- Kbar[b,he] = Wk[he,:].xbar[b,:] + S*bk[he]   (reduces Xpart + S inline)
__global__ __launch_bounds__(256) void k_kbar(const float4* __restrict__ Wk4,
                                              const float* __restrict__ bk,
                                              const float* __restrict__ wsum,
                                              const float4* __restrict__ Xp4,
                                              float* __restrict__ Kbar) {
    __shared__ float Xs[32][260];
    __shared__ float Wks[16][260];
    __shared__ float red[256];
    int t = threadIdx.x, he0 = blockIdx.x * 16;
    red[t] = wsum[t] + wsum[t + 256] + wsum[t + 512] + wsum[t + 768];
    __syncthreads();
    for (int s = 128; s > 0; s >>= 1) {
        if (t < s) red[t] += red[t + s];
        __syncthreads();
    }
    float S = red[0];
#pragma unroll
    for (int j = 0; j < 8; ++j) {
        int i4 = t + j * 256, r = i4 >> 6, c = i4 & 63;
        float4 s4 = make_float4(0.f, 0.f, 0.f, 0.f);
#pragma unroll
        for (int p = 0; p < 8; ++p) {
            float4 v = Xp4[(size_t)(r * 8 + p) * 64 + c];
            s4.x += v.x; s4.y += v.y; s4.z += v.z; s4.w += v.w;
        }
        *(float4*)&Xs[r][c * 4] = s4;
    }
#pragma unroll
    for (int j = 0; j < 4; ++j) {
        int i4 = t + j * 256, r = i4 >> 6, c = i4 & 63;
        *(float4*)&Wks[r][c * 4] = Wk4[(size_t)(he0 + r) * 64 + c];
    }
    __syncthreads();
    int bb = t & 31, rr = t >> 5;
    float a0 = 0.f, a1 = 0.f;
#pragma unroll 4
    for (int c = 0; c < 64; ++c) {
        float4 xv = *(float4*)&Xs[bb][c * 4];
        float4 w0 = *(float4*)&Wks[rr][c * 4];
        float4 w1 = *(float4*)&Wks[rr + 8][c * 4];
        a0 += DOT4(w0, xv);
        a1 += DOT4(w1, xv);
    }
    Kbar[(size_t)bb * HE + he0 + rr] = a0 + S * bk[he0 + rr];
    Kbar[(size_t)bb * HE + he0 + rr + 8] = a1 + S * bk[he0 + rr + 8];
}

// ---- u[b,h,d] = scale * sum_e Wq[h*E+e, d] * Kbar[b, h*E+e]
__global__ __launch_bounds__(256) void k_u(const float4* __restrict__ Wq4,
                                           const float* __restrict__ Kbar,
                                           float* __restrict__ u) {
    __shared__ float4 ps[4][64][9];
    int t = threadIdx.x, h = blockIdx.x, bg = blockIdx.y;
    int dq = t & 63, rep = t >> 6;
    float4 acc[8];
#pragma unroll
    for (int j = 0; j < 8; ++j) acc[j] = make_float4(0.f, 0.f, 0.f, 0.f);
    for (int el = 0; el < 64; ++el) {
        int e = rep * 64 + el;
        float4 wq = Wq4[(size_t)(h * E + e) * 64 + dq];
#pragma unroll
        for (int j = 0; j < 8; ++j) {
            float kb = Kbar[(size_t)(bg * 8 + j) * HE + h * E + e];
            acc[j].x += kb * wq.x; acc[j].y += kb * wq.y;
            acc[j].z += kb * wq.z; acc[j].w += kb * wq.w;
        }
    }
#pragma unroll
    for (int j = 0; j < 8; ++j) ps[rep][dq][j] = acc[j];
    __syncthreads();
    int js = t >> 6;
#pragma unroll
    for (int jj = 0; jj < 2; ++jj) {
        int j = js * 2 + jj;
        float4 s = ps[0][dq][j], s1 = ps[1][dq][j], s2 = ps[2][dq][j], s3 = ps[3][dq][j];
        s.x = (s.x + s1.x + s2.x + s3.x) * 0.0625f;
        s.y = (s.y + s1.y + s2.y + s3.y) * 0.0625f;
        s.z = (s.z + s1.z + s2.z + s3.z) * 0.0625f;
        s.w = (s.w + s1.w + s2.w + s3.w) * 0.0625f;
        *(float4*)&u[((size_t)(bg * 8 + j) * 8 + h) * D + dq * 4] = s;
    }
}

// ---- fused: logits -> z=exp(logit) -> Vpart[b,c,h,:] = sum_n z*x[n,:], Zpart[b,c,h] = sum_n z
__global__ __launch_bounds__(512) void k_attn(const float4* __restrict__ x4,
                                              const float* __restrict__ U,
                                              float* __restrict__ Vpart,
                                              float* __restrict__ Zpart) {
    __shared__ float xs[64][268];   // aliased as psv[8][64][33] after last use
    __shared__ float psL[8][64][9];
    __shared__ float z[8][128];
    int t = threadIdx.x, b = blockIdx.x, cch = blockIdx.y;
    int lane = t & 63, w = t >> 6;
    const float* ub = U + (size_t)b * HE;
    int n0 = cch * 128;
    int dbase = __builtin_amdgcn_readfirstlane(w * 32);
    float4 accV[8];
#pragma unroll
    for (int h = 0; h < 8; ++h) accV[h] = make_float4(0.f, 0.f, 0.f, 0.f);

    for (int st = 0; st < 2; ++st) {
        // stage 64 rows of x
#pragma unroll
        for (int j = 0; j < 8; ++j) {
            int i4 = t + j * 512, r = i4 >> 6, c = i4 & 63;
            *(float4*)&xs[r][c * 4] = x4[(size_t)(b * N + n0 + st * 64 + r) * 64 + c];
        }
        __syncthreads();
        // logits: row = lane, d-slice = dbase..dbase+31
        float accL[8] = {0.f, 0.f, 0.f, 0.f, 0.f, 0.f, 0.f, 0.f};
#pragma unroll
        for (int g = 0; g < 8; ++g) {
            int d = dbase + g * 4;
            float4 xv = *(float4*)&xs[lane][d];
#pragma unroll
            for (int h = 0; h < 8; ++h) {
                float4 uv = *(const float4*)&ub[h * D + d];
                accL[h] += DOT4(xv, uv);
            }
        }
#pragma unroll
        for (int h = 0; h < 8; ++h) psL[w][lane][h] = accL[h];
        __syncthreads();
        {
            int r = t & 63, h = t >> 6;
            float s = 0.f;
#pragma unroll
            for (int ww = 0; ww < 8; ++ww) s += psL[ww][r][h];
            z[h][st * 64 + r] = __expf(s);   // logits tiny -> no max subtraction needed
        }
        __syncthreads();
        // vbar accumulate from the same LDS tile: rep = w (8 rows), dq = lane
#pragma unroll
        for (int i = 0; i < 8; ++i) {
            int r = w * 8 + i;
            float4 xv = *(float4*)&xs[r][lane * 4];
#pragma unroll
            for (int h = 0; h < 8; ++h) {
                float zz = z[h][st * 64 + r];
                accV[h].x += zz * xv.x; accV[h].y += zz * xv.y;
                accV[h].z += zz * xv.z; accV[h].w += zz * xv.w;
            }
        }
        __syncthreads();   // xs reused next stage / as psv
    }
    // reduce accV over the 8 waves via scalar-padded LDS aliased onto xs (conflict-free, stride 33)
    float* psv = &xs[0][0];   // [8][64][33] = 16896 <= 64*268
#pragma unroll
    for (int h = 0; h < 8; ++h) {
        int base = (w * 64 + lane) * 33 + h * 4;
        psv[base + 0] = accV[h].x; psv[base + 1] = accV[h].y;
        psv[base + 2] = accV[h].z; psv[base + 3] = accV[h].w;
    }
    __syncthreads();
    {
        int dq2 = t & 63, h = t >> 6;
        float4 v = make_float4(0.f, 0.f, 0.f, 0.f);
#pragma unroll
        for (int rep = 0; rep < 8; ++rep) {
            int base = (rep * 64 + dq2) * 33 + h * 4;
            v.x += psv[base]; v.y += psv[base + 1]; v.z += psv[base + 2]; v.w += psv[base + 3];
        }
        *(float4*)&Vpart[(((size_t)(b * 8 + cch) * 8 + h) * 64 + dq2) * 4] = v;
    }
    {
        int h = t >> 6, i = t & 63;
        float zp = z[h][i] + z[h][i + 64];
#pragma unroll
        for (int off = 32; off > 0; off >>= 1) zp += __shfl_xor(zp, off);
        if (i == 0) Zpart[(size_t)(b * 8 + cch) * 8 + h] = zp;
    }
}

// ---- Vbar[b,h,d] = sum_c Vpart[b,c,h,d]
__global__ __launch_bounds__(256) void k_vred(const float4* __restrict__ Vp4,
                                              float4* __restrict__ Vbar4) {
    int g = blockIdx.x * 256 + threadIdx.x;   // 16384 float4s
    int d4 = g & 63, h = (g >> 6) & 7, b = g >> 9;
    float4 s = make_float4(0.f, 0.f, 0.f, 0.f);
#pragma unroll
    for (int c = 0; c < 8; ++c) {
        float4 v = Vp4[((size_t)(b * 8 + c) * 8 + h) * 64 + d4];
        s.x += v.x; s.y += v.y; s.z += v.z; s.w += v.w;
    }
    Vbar4[g] = s;
}

// ---- res[b,he] = (Wv[he,:].Vbar[b,h,:]) / Z[b,h] + bv[he]
__global__ __launch_bounds__(256) void k_result(const float4* __restrict__ Wv4,
                                                const float* __restrict__ bv,
                                                const float4* __restrict__ Vbar4,
                                                const float* __restrict__ Zpart,
                                                float* __restrict__ res) {
    __shared__ float Vs[32][260];
    __shared__ float Ws[16][260];
    int t = threadIdx.x, h = blockIdx.x;
    int he0 = h * E + blockIdx.y * 16;
#pragma unroll
    for (int j = 0; j < 8; ++j) {
        int i4 = t + j * 256, r = i4 >> 6, c = i4 & 63;
        *(float4*)&Vs[r][c * 4] = Vbar4[(size_t)(r * 8 + h) * 64 + c];
    }
#pragma unroll
    for (int j = 0; j < 4; ++j) {
        int i4 = t + j * 256, r = i4 >> 6, c = i4 & 63;
        *(float4*)&Ws[r][c * 4] = Wv4[(size_t)(he0 + r) * 64 + c];
    }
    __syncthreads();
    int bb = t & 31, rr = t >> 5;
    float a0 = 0.f, a1 = 0.f;
#pragma unroll 4
    for (int c = 0; c < 64; ++c) {
        float4 xv = *(float4*)&Vs[bb][c * 4];
        float4 w0 = *(float4*)&Ws[rr][c * 4];
        float4 w1 = *(float4*)&Ws[rr + 8][c * 4];
        a0 += DOT4(w0, xv);
        a1 += DOT4(w1, xv);
    }
    float zs = 0.f;
#pragma unroll
    for (int c = 0; c < 8; ++c) zs += Zpart[(size_t)(bb * 8 + c) * 8 + h];
    float inv = 1.0f / zs;
    res[(size_t)bb * HE + he0 + rr] = a0 * inv + bv[he0 + rr];
    res[(size_t)bb * HE + he0 + rr + 8] = a1 * inv + bv[he0 + rr + 8];
}

// ---- out[b,d] = Wo[d,:].res[b,:] + bo[d]   (full-k, no atomics)
__global__ __launch_bounds__(256) void k_out(const float4* __restrict__ Wo4,
                                             const float* __restrict__ bo,
                                             const float4* __restrict__ res4,
                                             float* __restrict__ out) {
    __shared__ float Rs[32][260];
    __shared__ float Ws[8][260];
    int t = threadIdx.x, d0 = blockIdx.x * 8;
    int bb = t & 31, rr = t >> 5;
    float a = 0.f;
    for (int ch = 0; ch < 8; ++ch) {
        int k4 = ch * 64;
#pragma unroll
        for (int j = 0; j < 8; ++j) {
            int i4 = t + j * 256, r = i4 >> 6, c = i4 & 63;
            *(float4*)&Rs[r][c * 4] = res4[(size_t)r * 512 + k4 + c];
        }
#pragma unroll
        for (int j = 0; j < 2; ++j) {
            int i4 = t + j * 256, r = i4 >> 6, c = i4 & 63;
            *(float4*)&Ws[r][c * 4] = Wo4[(size_t)(d0 + r) * 512 + k4 + c];
        }
        __syncthreads();
#pragma unroll 4
        for (int c = 0; c < 64; ++c) {
            float4 w = *(float4*)&Ws[rr][c * 4];
            float4 rv = *(float4*)&Rs[bb][c * 4];
            a += DOT4(w, rv);
        }
        __syncthreads();
    }
    out[(size_t)bb * D + d0 + rr] = a + bo[d0 + rr];
}

extern "C" void kernel_launch(void* const* d_in, const int* in_sizes, int n_in,
                              void* d_out, int out_size, void* d_ws, size_t ws_size,
                              hipStream_t stream) {
    const float* x    = (const float*)d_in[0];
    const float* Wq   = (const float*)d_in[1];
    // d_in[2] = bq : softmax-invariant, drops out
    const float* Wk   = (const float*)d_in[3];
    const float* bk   = (const float*)d_in[4];
    const float* Wv   = (const float*)d_in[5];
    const float* bv   = (const float*)d_in[6];
    const float* wsum = (const float*)d_in[7];
    // d_in[8] = bs : softmax-invariant, drops out
    const float* Wo   = (const float*)d_in[9];
    const float* bo   = (const float*)d_in[10];
    float* wsf   = (float*)d_ws;
    float* XPART = wsf + OFF_XPART;
    float* KBAR  = wsf + OFF_KBAR;
    float* U     = wsf + OFF_U;
    float* VPART = wsf + OFF_VPART;
    float* VBAR  = wsf + OFF_VBAR;
    float* ZPART = wsf + OFF_ZPART;
    float* RES   = wsf + OFF_RES;

    k_xbar<<<dim3(B, 8), 256, 0, stream>>>((const float4*)x, wsum, XPART);
    k_kbar<<<128, 256, 0, stream>>>((const float4*)Wk, bk, wsum, (const float4*)XPART, KBAR);
    k_u<<<dim3(H, 4), 256, 0, stream>>>((const float4*)Wq, KBAR, U);
    k_attn<<<dim3(B, 8), 512, 0, stream>>>((const float4*)x, U, VPART, ZPART);
    k_vred<<<64, 256, 0, stream>>>((const float4*)VPART, (float4*)VBAR);
    k_result<<<dim3(H, 16), 256, 0, stream>>>((const float4*)Wv, bv, (const float4*)VBAR, ZPART, RES);
    k_out<<<32, 256, 0, stream>>>((const float4*)Wo, bo, (const float4*)RES, (float*)d_out);
}

// Round 4
// 66.018 us; speedup vs baseline: 1.3050x; 1.3050x over previous
//
#include <hip/hip_runtime.h>

#define B 32
#define N 1024
#define D 256
#define H 8
#define E 256
#define HE 2048

// d_ws float offsets
#define OFF_XBAR  0        // [B][D]           8192
#define OFF_KBAR  8192     // [B][HE]          65536
#define OFF_U     73728    // [B][H][D]        65536 (atomic-accumulated, scale folded)
#define OFF_VPART 139264   // [B][8c][H][D]    524288
#define OFF_ZPART 663552   // [B][8c][H]       2048
#define OFF_RES   665600   // [B][HE]          65536

#define DOT4(a, v) ((a).x * (v).x + (a).y * (v).y + (a).z * (v).z + (a).w * (v).w)

// ---- xbar[b,d] = sum_n wsum[n]*x[b,n,d]  — final output, no partial round-trip.
// grid (B, 8 d-slices of 32 floats); per wave: 8 rows x 128B fragments.
__global__ __launch_bounds__(256) void k_xbar(const float4* __restrict__ x4,
                                              const float* __restrict__ wsum,
                                              float4* __restrict__ Xbar4) {
    __shared__ float4 ps[32][8];
    int t = threadIdx.x, b = blockIdx.x, dc = blockIdx.y;
    int dq = t & 7, rep = t >> 3;
    float4 acc = make_float4(0.f, 0.f, 0.f, 0.f);
#pragma unroll 4
    for (int i = 0; i < 32; ++i) {
        int n = i * 32 + rep;
        float w = wsum[n];
        float4 xv = x4[(size_t)(b * N + n) * 64 + dc * 8 + dq];
        acc.x += w * xv.x; acc.y += w * xv.y; acc.z += w * xv.z; acc.w += w * xv.w;
    }
    ps[rep][dq] = acc;
    __syncthreads();
    if (t < 8) {
        float4 s = make_float4(0.f, 0.f, 0.f, 0.f);
#pragma unroll
        for (int r = 0; r < 32; ++r) {
            float4 v = ps[r][t];
            s.x += v.x; s.y += v.y; s.z += v.z; s.w += v.w;
        }
        Xbar4[b * 64 + dc * 8 + t] = s;
    }
}

// ---- Kbar[b,he] = Wk[he,:].xbar[b,:] + S*bk[he]   — 256 blocks, 8-row tiles
__global__ __launch_bounds__(256) void k_kbar(const float4* __restrict__ Wk4,
                                              const float* __restrict__ bk,
                                              const float* __restrict__ wsum,
                                              const float4* __restrict__ Xbar4,
                                              float* __restrict__ Kbar) {
    __shared__ float Xs[32][260];
    __shared__ float Wks[8][260];
    __shared__ float red[256];
    int t = threadIdx.x, he0 = blockIdx.x * 8;
    red[t] = wsum[t] + wsum[t + 256] + wsum[t + 512] + wsum[t + 768];
#pragma unroll
    for (int j = 0; j < 8; ++j) {
        int i4 = t + j * 256, r = i4 >> 6, c = i4 & 63;
        *(float4*)&Xs[r][c * 4] = Xbar4[r * 64 + c];
    }
#pragma unroll
    for (int j = 0; j < 2; ++j) {
        int i4 = t + j * 256, r = i4 >> 6, c = i4 & 63;
        *(float4*)&Wks[r][c * 4] = Wk4[(size_t)(he0 + r) * 64 + c];
    }
    __syncthreads();
    for (int s = 128; s > 0; s >>= 1) {
        if (t < s) red[t] += red[t + s];
        __syncthreads();
    }
    float S = red[0];
    int bb = t & 31, rr = t >> 5;
    float a = 0.f;
#pragma unroll 4
    for (int c = 0; c < 64; ++c) {
        float4 xv = *(float4*)&Xs[bb][c * 4];
        float4 w = *(float4*)&Wks[rr][c * 4];
        a += DOT4(w, xv);
    }
    Kbar[(size_t)bb * HE + he0 + rr] = a + S * bk[he0 + rr];
}

// ---- U[b,h,d] += scale * sum_{e in slice} Wq[h*E+e, d] * Kbar[b,h*E+e]
// grid (H, 4 b-groups, 2 e-slices); U pre-zeroed, atomicAdd partials.
__global__ __launch_bounds__(256) void k_u(const float4* __restrict__ Wq4,
                                           const float* __restrict__ Kbar,
                                           float* __restrict__ U) {
    __shared__ float4 psv[4][64][9];
    int t = threadIdx.x, h = blockIdx.x, bg = blockIdx.y, es = blockIdx.z;
    int dq = t & 63, rep = t >> 6;
    float4 acc[8];
#pragma unroll
    for (int j = 0; j < 8; ++j) acc[j] = make_float4(0.f, 0.f, 0.f, 0.f);
    for (int i = 0; i < 32; ++i) {
        int e = es * 128 + rep * 32 + i;
        float4 wq = Wq4[(size_t)(h * E + e) * 64 + dq];
#pragma unroll
        for (int j = 0; j < 8; ++j) {
            float kb = Kbar[(size_t)(bg * 8 + j) * HE + h * E + e];  // uniform -> s_load
            acc[j].x += kb * wq.x; acc[j].y += kb * wq.y;
            acc[j].z += kb * wq.z; acc[j].w += kb * wq.w;
        }
    }
#pragma unroll
    for (int j = 0; j < 8; ++j) psv[rep][dq][j] = acc[j];
    __syncthreads();
    int jg = t >> 6;
#pragma unroll
    for (int jj = 0; jj < 2; ++jj) {
        int j = jg * 2 + jj;
        float4 s0 = psv[0][dq][j], s1 = psv[1][dq][j], s2 = psv[2][dq][j], s3 = psv[3][dq][j];
        float* up = &U[((size_t)(bg * 8 + j) * H + h) * D + dq * 4];
        atomicAdd(up + 0, (s0.x + s1.x + s2.x + s3.x) * 0.0625f);
        atomicAdd(up + 1, (s0.y + s1.y + s2.y + s3.y) * 0.0625f);
        atomicAdd(up + 2, (s0.z + s1.z + s2.z + s3.z) * 0.0625f);
        atomicAdd(up + 3, (s0.w + s1.w + s2.w + s3.w) * 0.0625f);
    }
}

// ---- fused: logits -> z=exp(logit) -> Vpart[b,c,h,:] = sum_n z*x[n,:], Zpart[b,c,h] = sum_n z
__global__ __launch_bounds__(512) void k_attn(const float4* __restrict__ x4,
                                              const float* __restrict__ U,
                                              float* __restrict__ Vpart,
                                              float* __restrict__ Zpart) {
    __shared__ float xs[64][268];   // aliased as psv[8][64][33] after last use
    __shared__ float psL[8][64][9];
    __shared__ float z[8][128];
    int t = threadIdx.x, b = blockIdx.x, cch = blockIdx.y;
    int lane = t & 63, w = t >> 6;
    const float* ub = U + (size_t)b * HE;
    int n0 = cch * 128;
    int dbase = __builtin_amdgcn_readfirstlane(w * 32);
    float4 accV[8];
#pragma unroll
    for (int h = 0; h < 8; ++h) accV[h] = make_float4(0.f, 0.f, 0.f, 0.f);

    for (int st = 0; st < 2; ++st) {
#pragma unroll
        for (int j = 0; j < 8; ++j) {
            int i4 = t + j * 512, r = i4 >> 6, c = i4 & 63;
            *(float4*)&xs[r][c * 4] = x4[(size_t)(b * N + n0 + st * 64 + r) * 64 + c];
        }
        __syncthreads();
        float accL[8] = {0.f, 0.f, 0.f, 0.f, 0.f, 0.f, 0.f, 0.f};
#pragma unroll
        for (int g = 0; g < 8; ++g) {
            int d = dbase + g * 4;
            float4 xv = *(float4*)&xs[lane][d];
#pragma unroll
            for (int h = 0; h < 8; ++h) {
                float4 uv = *(const float4*)&ub[h * D + d];  // uniform -> s_load_dwordx4
                accL[h] += DOT4(xv, uv);
            }
        }
#pragma unroll
        for (int h = 0; h < 8; ++h) psL[w][lane][h] = accL[h];
        __syncthreads();
        {
            int r = t & 63, h = t >> 6;
            float s = 0.f;
#pragma unroll
            for (int ww = 0; ww < 8; ++ww) s += psL[ww][r][h];
            z[h][st * 64 + r] = __expf(s);   // logits tiny -> no max subtraction needed
        }
        __syncthreads();
#pragma unroll
        for (int i = 0; i < 8; ++i) {
            int r = w * 8 + i;
            float4 xv = *(float4*)&xs[r][lane * 4];
#pragma unroll
            for (int h = 0; h < 8; ++h) {
                float zz = z[h][st * 64 + r];
                accV[h].x += zz * xv.x; accV[h].y += zz * xv.y;
                accV[h].z += zz * xv.z; accV[h].w += zz * xv.w;
            }
        }
        __syncthreads();
    }
    float* psv = &xs[0][0];   // [8][64][33]
#pragma unroll
    for (int h = 0; h < 8; ++h) {
        int base = (w * 64 + lane) * 33 + h * 4;
        psv[base + 0] = accV[h].x; psv[base + 1] = accV[h].y;
        psv[base + 2] = accV[h].z; psv[base + 3] = accV[h].w;
    }
    __syncthreads();
    {
        int dq2 = t & 63, h = t >> 6;
        float4 v = make_float4(0.f, 0.f, 0.f, 0.f);
#pragma unroll
        for (int rep = 0; rep < 8; ++rep) {
            int base = (rep * 64 + dq2) * 33 + h * 4;
            v.x += psv[base]; v.y += psv[base + 1]; v.z += psv[base + 2]; v.w += psv[base + 3];
        }
        *(float4*)&Vpart[(((size_t)(b * 8 + cch) * 8 + h) * 64 + dq2) * 4] = v;
    }
    {
        int h = t >> 6, i = t & 63;
        float zp = z[h][i] + z[h][i + 64];
#pragma unroll
        for (int off = 32; off > 0; off >>= 1) zp += __shfl_xor(zp, off);
        if (i == 0) Zpart[(size_t)(b * 8 + cch) * 8 + h] = zp;
    }
}

// ---- res[b,he] = (Wv[he,:].vbar[b,h,:])/Z[b,h] + bv[he]  — Vpart reduced inline
__global__ __launch_bounds__(256) void k_result(const float4* __restrict__ Wv4,
                                                const float* __restrict__ bv,
                                                const float4* __restrict__ Vp4,
                                                const float* __restrict__ Zpart,
                                                float* __restrict__ res) {
    __shared__ float Vs[32][260];
    __shared__ float Ws[16][260];
    int t = threadIdx.x, h = blockIdx.x;
    int he0 = h * E + blockIdx.y * 16;
#pragma unroll
    for (int j = 0; j < 8; ++j) {
        int i4 = t + j * 256, r = i4 >> 6, c = i4 & 63;
        float4 s = make_float4(0.f, 0.f, 0.f, 0.f);
#pragma unroll
        for (int cc = 0; cc < 8; ++cc) {
            float4 v = Vp4[((size_t)(r * 8 + cc) * 8 + h) * 64 + c];
            s.x += v.x; s.y += v.y; s.z += v.z; s.w += v.w;
        }
        *(float4*)&Vs[r][c * 4] = s;
    }
#pragma unroll
    for (int j = 0; j < 4; ++j) {
        int i4 = t + j * 256, r = i4 >> 6, c = i4 & 63;
        *(float4*)&Ws[r][c * 4] = Wv4[(size_t)(he0 + r) * 64 + c];
    }
    __syncthreads();
    int bb = t & 31, rr = t >> 5;
    float a0 = 0.f, a1 = 0.f;
#pragma unroll 4
    for (int c = 0; c < 64; ++c) {
        float4 xv = *(float4*)&Vs[bb][c * 4];
        float4 w0 = *(float4*)&Ws[rr][c * 4];
        float4 w1 = *(float4*)&Ws[rr + 8][c * 4];
        a0 += DOT4(w0, xv);
        a1 += DOT4(w1, xv);
    }
    float zs = 0.f;
#pragma unroll
    for (int cc = 0; cc < 8; ++cc) zs += Zpart[(size_t)(bb * 8 + cc) * 8 + h];
    float inv = 1.0f / zs;
    res[(size_t)bb * HE + he0 + rr] = a0 * inv + bv[he0 + rr];
    res[(size_t)bb * HE + he0 + rr + 8] = a1 * inv + bv[he0 + rr + 8];
}

// ---- out[b,d] += Wo[d, kslice].res[b, kslice] (+bo)  — 256 blocks, d_out pre-zeroed
__global__ __launch_bounds__(256) void k_out(const float4* __restrict__ Wo4,
                                             const float* __restrict__ bo,
                                             const float4* __restrict__ res4,
                                             float* __restrict__ out) {
    __shared__ float Rs[32][260];
    __shared__ float Ws[8][260];
    int t = threadIdx.x, d0 = blockIdx.x * 8;
    int k4 = blockIdx.y * 64;
#pragma unroll
    for (int j = 0; j < 8; ++j) {
        int i4 = t + j * 256, r = i4 >> 6, c = i4 & 63;
        *(float4*)&Rs[r][c * 4] = res4[(size_t)r * 512 + k4 + c];
    }
#pragma unroll
    for (int j = 0; j < 2; ++j) {
        int i4 = t + j * 256, r = i4 >> 6, c = i4 & 63;
        *(float4*)&Ws[r][c * 4] = Wo4[(size_t)(d0 + r) * 512 + k4 + c];
    }
    __syncthreads();
    int bb = t & 31, rr = t >> 5;
    float a = 0.f;
#pragma unroll 4
    for (int c = 0; c < 64; ++c) {
        float4 w = *(float4*)&Ws[rr][c * 4];
        float4 rv = *(float4*)&Rs[bb][c * 4];
        a += DOT4(w, rv);
    }
    if (blockIdx.y == 0) a += bo[d0 + rr];
    atomicAdd(&out[(size_t)bb * D + d0 + rr], a);
}

extern "C" void kernel_launch(void* const* d_in, const int* in_sizes, int n_in,
                              void* d_out, int out_size, void* d_ws, size_t ws_size,
                              hipStream_t stream) {
    const float* x    = (const float*)d_in[0];
    const float* Wq   = (const float*)d_in[1];
    // d_in[2] = bq : softmax-invariant, drops out
    const float* Wk   = (const float*)d_in[3];
    const float* bk   = (const float*)d_in[4];
    const float* Wv   = (const float*)d_in[5];
    const float* bv   = (const float*)d_in[6];
    const float* wsum = (const float*)d_in[7];
    // d_in[8] = bs : softmax-invariant, drops out
    const float* Wo   = (const float*)d_in[9];
    const float* bo   = (const float*)d_in[10];
    float* wsf   = (float*)d_ws;
    float* XBAR  = wsf + OFF_XBAR;
    float* KBAR  = wsf + OFF_KBAR;
    float* U     = wsf + OFF_U;
    float* VPART = wsf + OFF_VPART;
    float* ZPART = wsf + OFF_ZPART;
    float* RES   = wsf + OFF_RES;

    hipMemsetAsync(U, 0, (size_t)B * H * D * 4, stream);
    hipMemsetAsync(d_out, 0, (size_t)B * D * 4, stream);

    k_xbar<<<dim3(B, 8), 256, 0, stream>>>((const float4*)x, wsum, (float4*)XBAR);
    k_kbar<<<256, 256, 0, stream>>>((const float4*)Wk, bk, wsum, (const float4*)XBAR, KBAR);
    k_u<<<dim3(H, 4, 2), 256, 0, stream>>>((const float4*)Wq, KBAR, U);
    k_attn<<<dim3(B, 8), 512, 0, stream>>>((const float4*)x, U, VPART, ZPART);
    k_result<<<dim3(H, 16), 256, 0, stream>>>((const float4*)Wv, bv, (const float4*)VPART, ZPART, RES);
    k_out<<<dim3(32, 8), 256, 0, stream>>>((const float4*)Wo, bo, (const float4*)RES, (float*)d_out);
}